// Round 12
// baseline (241.928 us; speedup 1.0000x reference)
//
#include <hip/hip_runtime.h>
#include <hip/hip_fp16.h>

// NNConv on MI355X. msg[E x 32] = Z[E x 4096] @ w2r[4096 x 32],
// Z[e, c*32+i] = h[e,c]*xs[e,i] built on the fly in fp16 A-fragments via
// v_pk_mul_f16.
// Round 22: consolidation + depth. Ledger (R11-R21): atomics, launch
// count, B-source, h-path, MFMA density, wave count all eliminated;
// best remains R11's 134us core, which uniquely had FULL grid residency
// (116 regs/wave -> 6252/6252 waves resident). This round: R17's
// 2-launch scheme + R11's exact core (4 waves x 64 edges, 2 groups,
// split-slice hTq 8KB, barrier-free L2-direct B) with prefetch deepened
// 2 -> 4 half-chunk register buffers (+32 VGPR; (256,2) cap =
// 1024/(2*4) = 128 by the refitted cap law; live ~117+32AGPR -> still
// full residency). Coverage ~150 -> ~450 cy of the per-column stall.

#define NN 25000
#define EE 400000

typedef _Float16 f16x8 __attribute__((ext_vector_type(8)));
typedef float    f32x16 __attribute__((ext_vector_type(16)));

// ---------------- launch 1: pack w1/w2/b2 + out = x@root + bias ----------------
__global__ __launch_bounds__(256) void prep_final_kernel(
    const float* __restrict__ x, const float* __restrict__ root,
    const float* __restrict__ bias,
    const float* __restrict__ w1, const float* __restrict__ w2,
    const float* __restrict__ b2,
    _Float16* __restrict__ w2p, _Float16* __restrict__ w1p, _Float16* __restrict__ b2p,
    float* __restrict__ out)
{
    const int t = blockIdx.x * 256 + threadIdx.x;

    if (t < 131072) {
        int j = t & 7, lane = (t >> 3) & 63, ih = (t >> 9) & 1, c = t >> 10;
        w2p[t] = (_Float16)w2[c * 1024 + (ih * 16 + ((lane >> 5) << 3) + j) * 32 + (lane & 31)];
    } else if (t < 135168) {
        int u = t - 131072;
        int j = u & 7, lane = (u >> 3) & 63, kk = (u >> 9) & 1, r = u >> 10;
        w1p[u] = (_Float16)w1[(kk * 16 + ((lane >> 5) << 3) + j) * 128 + r * 32 + (lane & 31)];
    } else if (t < 136192) {
        int u = t - 135168;
        int j = u & 7, lane = (u >> 3) & 63, ih = u >> 9;
        b2p[u] = (_Float16)b2[(ih * 16 + ((lane >> 5) << 3) + j) * 32 + (lane & 31)];
    }

    int n = t >> 5, o = t & 31;
    float acc = bias[o];
    const float* xr = x + (n << 5);
#pragma unroll
    for (int i = 0; i < 32; ++i)
        acc = fmaf(xr[i], root[(i << 5) + o], acc);
    out[t] = acc;
}

// ---------------- launch 2: edge kernel (R11 core, 4-deep half-chunk dbuf) ----------------
// 256 thr = 4 waves x 64 edges (2 groups of 32) = 256 edges/block, 1563 blocks.
__global__ __launch_bounds__(256, 2) void edge_kernel(
    const float*    __restrict__ x,
    const int*      __restrict__ ei,
    const float*    __restrict__ ea,
    const float*    __restrict__ b1,
    const _Float16* __restrict__ w2p,
    const _Float16* __restrict__ w1p,
    const _Float16* __restrict__ b2p,
    float* __restrict__ out)
{
    __shared__ unsigned short hTq[4][16][32][2];           // 8 KB: 16-slot split hT

    const int t    = threadIdx.x;
    const int w    = t >> 6;
    const int lane = t & 63;
    const int l    = lane & 31;
    const int half = lane >> 5;

    const int  ebraw = blockIdx.x * 256 + w * 64;
    const bool live  = (ebraw + 64) <= EE;                 // wave-uniform
    const int  ebw   = live ? ebraw : (EE - 64);

    union u8h { f16x8 v; __half2 h2[4]; };

    // ---- w2 half-chunks (2 cols = 4 frags) read DIRECTLY from global ----
    // half-chunk hc: fragment fi at f16x8 element (hc*4 + fi)*64 + lane.
    const f16x8* __restrict__ w2f = (const f16x8*)w2p;

    f16x8 H0[4], H1[4], H2[4], H3[4];                      // 4-deep buffers
    auto loadHalf = [&](int hc, f16x8 (&B)[4]) {
        const f16x8* p = w2f + (size_t)hc * 256 + lane;
#pragma unroll
        for (int fi = 0; fi < 4; ++fi) B[fi] = p[fi * 64];
    };
    loadHalf(0, H0);                   // get loads flying before reg setup
    loadHalf(1, H1);
    loadHalf(2, H2);
    loadHalf(3, H3);

    // ---- persistent edge-attr fragments (fp16), 2 groups; read ONCE ----
    u8h eaf[2][2];
#pragma unroll
    for (int g = 0; g < 2; ++g)
#pragma unroll
        for (int kk = 0; kk < 2; ++kk) {
            const float* p = ea + (size_t)(ebw + g * 32 + l) * 32 + kk * 16 + half * 8;
            float4 a0 = *(const float4*)p;
            float4 a1 = *(const float4*)(p + 4);
            eaf[g][kk].h2[0] = __float22half2_rn(make_float2(a0.x, a0.y));
            eaf[g][kk].h2[1] = __float22half2_rn(make_float2(a0.z, a0.w));
            eaf[g][kk].h2[2] = __float22half2_rn(make_float2(a1.x, a1.y));
            eaf[g][kk].h2[3] = __float22half2_rn(make_float2(a1.z, a1.w));
        }

    // ---- gather xs rows (fp16 pairs) for 2 groups ----
    __half2 xs0[8], xs1[8];
    {
        int s0 = ei[ebw + l], s1 = ei[ebw + 32 + l];
#pragma unroll
        for (int ih = 0; ih < 2; ++ih) {
            float4 a0 = *(const float4*)(x + s0 * 32 + ih * 16 + half * 8);
            float4 a1 = *(const float4*)(x + s0 * 32 + ih * 16 + half * 8 + 4);
            xs0[ih*4+0] = __float22half2_rn(make_float2(a0.x, a0.y));
            xs0[ih*4+1] = __float22half2_rn(make_float2(a0.z, a0.w));
            xs0[ih*4+2] = __float22half2_rn(make_float2(a1.x, a1.y));
            xs0[ih*4+3] = __float22half2_rn(make_float2(a1.z, a1.w));
            float4 c0 = *(const float4*)(x + s1 * 32 + ih * 16 + half * 8);
            float4 c1 = *(const float4*)(x + s1 * 32 + ih * 16 + half * 8 + 4);
            xs1[ih*4+0] = __float22half2_rn(make_float2(c0.x, c0.y));
            xs1[ih*4+1] = __float22half2_rn(make_float2(c0.z, c0.w));
            xs1[ih*4+2] = __float22half2_rn(make_float2(c1.x, c1.y));
            xs1[ih*4+3] = __float22half2_rn(make_float2(c1.z, c1.w));
        }
    }

    f32x16 acc0, acc1;
#pragma unroll
    for (int i = 0; i < 16; ++i) { acc0[i] = 0.f; acc1[i] = 0.f; }

    unsigned held[8];                        // rows 16-31 of current slice, (g0,g1) packed

    // ---- phase-1 slice for r: rows 0-15 -> hTq slots now, rows 16-31 -> held ----
    auto phase1 = [&](int r) {
        f16x8 w1f0 = *(const f16x8*)(w1p + ((r * 2 + 0) * 64 + lane) * 8);
        f16x8 w1f1 = *(const f16x8*)(w1p + ((r * 2 + 1) * 64 + lane) * 8);
#pragma unroll
        for (int g = 0; g < 2; ++g) {
            f32x16 h;
#pragma unroll
            for (int i = 0; i < 16; ++i) h[i] = 0.f;
            h = __builtin_amdgcn_mfma_f32_32x32x16_f16(w1f0, eaf[g][0].v, h, 0, 0, 0);
            h = __builtin_amdgcn_mfma_f32_32x32x16_f16(w1f1, eaf[g][1].v, h, 0, 0, 0);
#pragma unroll
            for (int i = 0; i < 16; ++i) {
                int row = (i & 3) + ((i >> 2) << 3) + (half << 2);   // verified C/D map
                float hv = fmaxf(h[i] + b1[r * 32 + row], 0.f);
                unsigned short us = __half_as_ushort(__float2half(hv));
                if (i < 8) {
                    hTq[w][row][l][g] = us;                  // rows 0-15: slot == row
                } else {
                    int j = i - 8;                           // rows 16-31: hold in regs
                    if (g == 0) held[j] = us;
                    else        held[j] |= (unsigned)us << 16;
                }
            }
        }
    };

    // writes held rows into slots (wave-private; between chunk q=3 and q=4)
    auto flushHeld = [&]() {
#pragma unroll
        for (int j = 0; j < 8; ++j) {
            int slot = (j & 3) + ((j >> 2) << 3) + (half << 2);   // row-16
            *(unsigned*)&hTq[w][slot][l][0] = held[j];
        }
    };

    // compute one half-chunk (2 c-columns) from register fragments
    auto computeHalf = [&](int q4, int hh, const f16x8 (&B)[4]) {
#pragma unroll
        for (int c2 = 0; c2 < 2; ++c2) {
            const int cl = hh * 2 + c2;
            unsigned u = *(const unsigned*)&hTq[w][(q4 << 2) + cl][l][0];
            __half2 hp = *reinterpret_cast<const __half2*>(&u);
            __half2 h0 = __half2half2(__low2half(hp));       // dup for group 0
            __half2 h1 = __half2half2(__high2half(hp));      // dup for group 1
#pragma unroll
            for (int ih = 0; ih < 2; ++ih) {
                f16x8 bfr = B[c2 * 2 + ih];
                u8h A;
#pragma unroll
                for (int p = 0; p < 4; ++p)
                    A.h2[p] = __hmul2(h0, xs0[ih * 4 + p]);      // v_pk_mul_f16
                acc0 = __builtin_amdgcn_mfma_f32_32x32x16_f16(A.v, bfr, acc0, 0, 0, 0);
#pragma unroll
                for (int p = 0; p < 4; ++p)
                    A.h2[p] = __hmul2(h1, xs1[ih * 4 + p]);
                acc1 = __builtin_amdgcn_mfma_f32_32x32x16_f16(A.v, bfr, acc1, 0, 0, 0);
            }
        }
    };

    // ---- pipeline: no barriers. 4 buffers -> loads run 2 half-chunk pairs
    // (~3 computeHalf) ahead. Tail loads overread into w1p/b2p workspace
    // (valid memory, values unused). ----
    phase1(0);
#pragma unroll 1
    for (int r = 0; r < 4; ++r) {
        if (r > 0) phase1(r);              // wave-private hTq: no barrier needed
#pragma unroll 1
        for (int q = 0; q < 8; ++q) {
            const int cc = r * 8 + q;
            const int hc = cc * 2;
            if (q == 4) flushHeld();       // rows 16-31 into the 16 slots
            if ((hc & 2) == 0) {
                computeHalf(q & 3, 0, H0); loadHalf(hc + 4, H0);
                computeHalf(q & 3, 1, H1); loadHalf(hc + 5, H1);
            } else {
                computeHalf(q & 3, 0, H2); loadHalf(hc + 4, H2);
                computeHalf(q & 3, 1, H3); loadHalf(hc + 5, H3);
            }
        }
    }

    // ---- b2 contribution: extra K-step with h == 1 (A-fragment = xs, no VALU) ----
#pragma unroll
    for (int ih = 0; ih < 2; ++ih) {
        f16x8 bfr = *(const f16x8*)(b2p + (ih * 64 + lane) * 8);
        u8h A;
#pragma unroll
        for (int p = 0; p < 4; ++p) A.h2[p] = xs0[ih * 4 + p];
        acc0 = __builtin_amdgcn_mfma_f32_32x32x16_f16(A.v, bfr, acc0, 0, 0, 0);
#pragma unroll
        for (int p = 0; p < 4; ++p) A.h2[p] = xs1[ih * 4 + p];
        acc1 = __builtin_amdgcn_mfma_f32_32x32x16_f16(A.v, bfr, acc1, 0, 0, 0);
    }

    // ---- scatter-add into out (base written by launch 1); skip clamped tails ----
    if (live) {
#pragma unroll
        for (int i = 0; i < 16; ++i) {
            int el = (i & 3) + ((i >> 2) << 3) + (half << 2);
            atomicAdd(out + (size_t)ei[EE + ebw +      el] * 32 + l, acc0[i]);
            atomicAdd(out + (size_t)ei[EE + ebw + 32 + el] * 32 + l, acc1[i]);
        }
    }
}

extern "C" void kernel_launch(void* const* d_in, const int* in_sizes, int n_in,
                              void* d_out, int out_size, void* d_ws, size_t ws_size,
                              hipStream_t stream) {
    const float* x    = (const float*)d_in[0];
    const int*   ei   = (const int*)  d_in[1];
    const float* ea   = (const float*)d_in[2];
    const float* w1   = (const float*)d_in[3];
    const float* b1   = (const float*)d_in[4];
    const float* w2   = (const float*)d_in[5];
    const float* b2   = (const float*)d_in[6];
    const float* root = (const float*)d_in[7];
    const float* bias = (const float*)d_in[8];
    float* out = (float*)d_out;

    _Float16* w2p = (_Float16*)d_ws;                      // 262144 B
    _Float16* w1p = (_Float16*)((char*)d_ws + 262144);    //   8192 B
    _Float16* b2p = (_Float16*)((char*)d_ws + 270336);    //   2048 B
    // (edge kernel tail prefetch may overread up to ~278 KB of d_ws)

    prep_final_kernel<<<(NN * 32) / 256, 256, 0, stream>>>(
        x, root, bias, w1, w2, b2, w2p, w1p, b2p, out);

    edge_kernel<<<(EE + 255) / 256, 256, 0, stream>>>(
        x, ei, ea, b1, w2p, w1p, b2p, out);
}